// Round 6
// baseline (192.925 us; speedup 1.0000x reference)
//
#include <hip/hip_runtime.h>
#include <stdint.h>

// Volterra layer: out = conv3x3(x,w1) + conv3x3(quad,w2) + (b1 + 4*b2)
// quad = sum over 4 shifts of clip(x * circular_shift(x), -1, 1)
// B=8, C=64, H=W=256. Convs are zero-pad SAME; shifts are circular.

typedef short s16x8 __attribute__((ext_vector_type(8)));
typedef float f32x4 __attribute__((ext_vector_type(4)));

__device__ __forceinline__ float clip1(float v) { return fminf(fmaxf(v, -1.f), 1.f); }

__device__ __forceinline__ unsigned short f2bf(float f) {
    union { float f; unsigned u; } v; v.f = f;
    unsigned u = v.u;
    return (unsigned short)((u + 0x7fffu + ((u >> 16) & 1u)) >> 16);
}

__device__ __forceinline__ float bf2f(unsigned short u) {
    union { unsigned v; float f; } t; t.v = ((unsigned)u) << 16; return t.f;
}

// ---------------------------------------------------------------------------
// Kernel 1: weights -> bf16, layout Wb[kh][cc][co][kw*32+cci]
// ---------------------------------------------------------------------------
__global__ void prep_w(const float* __restrict__ w1, const float* __restrict__ w2,
                       unsigned short* __restrict__ Wb) {
    int idx = blockIdx.x * 256 + threadIdx.x;   // exactly 73728 threads
    int kk = idx % 96;
    int rest = idx / 96;
    int co = rest & 63; rest >>= 6;
    int cc = rest & 3;
    int kh = rest >> 2;
    int kw = kk >> 5;
    int cci = kk & 31;
    int c2 = cc * 32 + cci;
    const float* src = (c2 < 64) ? w1 : w2;
    int ci = c2 & 63;
    Wb[idx] = f2bf(src[((co * 64 + ci) * 3 + kh) * 3 + kw]);
}

// ---------------------------------------------------------------------------
// Kernel 2 (v3): quad/pack, pixel-half split for occupancy.
// Block = (b=XCD, h, whalf), 512 thr. X[3][64][134] = 51.5 KB -> 3 blocks/CU
// (24 waves vs prep_u2's 8). Stride 134 (67 dwords, odd) => conflict-free
// phase-2 reads; stores are 2x ushort2 (rows only 4B-aligned).
// U[(b*256+h)*256+w][c2]: c2 0-63 = bf16(x), 64-127 = bf16(quad).
// ---------------------------------------------------------------------------
__global__ __launch_bounds__(512, 1) void prep_u3(const float* __restrict__ x,
                                                  unsigned short* __restrict__ U) {
    __shared__ unsigned short X[3][64][134];
    int bid = blockIdx.x;           // 4096 blocks
    int b = bid & 7;                // image = XCD
    int rest = bid >> 3;            // 0..511
    int h = rest >> 1;
    int whalf = rest & 1;
    int w0 = whalf << 7;            // 0 or 128
    int tid = threadIdx.x;

    // phase 1: rows {h-1,h,h+1} (circular), 64 ch, cols [w0-4, w0+128) = 33 quads
    for (int it = 0; it < 13; ++it) {
        int idx = tid + (it << 9);
        if (idx < 6336) {
            int k = idx % 33;           // quad index 0..32
            int rc = idx / 33;          // 0..191
            int c = rc & 63;
            int r = rc >> 6;            // 0..2
            int gr = (h + r + 255) & 255;
            int cw = w0 - 4 + (k << 2);
            if (cw < 0) cw += 256;      // circular (whalf==0, k==0 -> 252)
            const float4 v = *(const float4*)(x + (((size_t)(b * 64 + c)) << 16)
                                                + (gr << 8) + cw);
            ushort2 lo, hi;
            lo.x = f2bf(v.x); lo.y = f2bf(v.y);
            hi.x = f2bf(v.z); hi.y = f2bf(v.w);
            *(ushort2*)&X[r][c][(k << 2)]     = lo;
            *(ushort2*)&X[r][c][(k << 2) + 2] = hi;
        }
    }
    __syncthreads();

    // phase 2: lane=channel, wave owns 16 pixels; register-chained w-1 terms
    int c  = tid & 63;
    int wv = tid >> 6;              // 0..7
    int pl0 = wv << 4;              // local pixel base
    float pxc = bf2f(X[1][c][pl0 + 3]);   // x[h  ][w-1]
    float pxu = bf2f(X[0][c][pl0 + 3]);   // x[h-1][w-1]
    float pxd = bf2f(X[2][c][pl0 + 3]);   // x[h+1][w-1]
    size_t base = (size_t)(((b << 8) + h)) << 8;
#pragma unroll 4
    for (int i = 0; i < 16; ++i) {
        int pl = pl0 + i;
        int xcol = pl + 4;
        unsigned short xcb = X[1][c][xcol];
        float xc = bf2f(xcb);
        float xu = bf2f(X[0][c][xcol]);
        float xd = bf2f(X[2][c][xcol]);
        // shifts: (0,1)->x[h-1][w]; (1,-1)->x[h+1][w-1]; (1,0)->x[h][w-1]; (1,1)->x[h-1][w-1]
        float q = clip1(xc * xu) + clip1(xc * pxd) + clip1(xc * pxc) + clip1(xc * pxu);
        size_t po = (base + w0 + pl) << 7;
        U[po + c]      = xcb;
        U[po + 64 + c] = f2bf(q);
        pxc = xc; pxu = xu; pxd = xd;
    }
}

// ---------------------------------------------------------------------------
// Kernel 3 (v4b): input-row-stationary implicit-GEMM conv, 4 output rows/blk.
// 1024 thr = 16 waves (rowsel 0..3 x pixel-quarter 0..3). Proven LDS layout
// (Ilds stride 40, Alds stride 104: conflict-free per 16-lane phase).
// Register budget note: acc = 64 AGPR + 64 arch VGPR = 128/wave -> exactly
// 4 waves/SIMD (16 waves/CU, 1 resident block). Do NOT grow arch VGPRs.
// Added T5 s_setprio around the MFMA cluster.
// ---------------------------------------------------------------------------
__global__ __launch_bounds__(1024, 2) void conv4(
        const unsigned short* __restrict__ U,
        const unsigned short* __restrict__ Wb,
        const float* __restrict__ b1, const float* __restrict__ b2,
        float* __restrict__ out) {
    __shared__ unsigned short Alds[3][64][104];   // 39936 B
    __shared__ unsigned short Ib[2][258][40];     // 41280 B

    int bid = blockIdx.x;
    int logical = ((bid & 7) << 6) + (bid >> 3);  // XCD k -> batch image k
    int b = logical >> 6;
    int h0 = (logical & 63) << 2;                 // 4 output rows h0..h0+3
    int tid = threadIdx.x;
    int wid = tid >> 6;
    int ln = tid & 63;
    int lr = ln & 15;        // MFMA A-row / C col
    int lq = ln >> 4;        // MFMA k-group / C row-group
    int rowsel = wid >> 2;   // which of the 4 output rows
    int pq = wid & 3;        // pixel quarter (64 px)
    int o = h0 + rowsel;

    f32x4 acc[4][4];
#pragma unroll
    for (int m = 0; m < 4; m++)
#pragma unroll
        for (int n = 0; n < 4; n++) {
            acc[m][n][0] = 0.f; acc[m][n][1] = 0.f; acc[m][n][2] = 0.f; acc[m][n][3] = 0.f;
        }

    const size_t ubase = ((size_t)b) << 23;

    int cur = 0;
    for (int cc = 0; cc < 4; cc++) {
        // ---- stage weights for all 3 kh of this cc
        for (int i = tid; i < 2304; i += 1024) {
            int kh = i / 768;
            int rem = i - kh * 768;
            int co = rem / 12;
            int kk = (rem - co * 12) << 3;
            *(uint4*)&Alds[kh][co][kk] =
                *(const uint4*)&Wb[(((size_t)((kh * 4 + cc) * 64 + co)) * 96) + kk];
        }
        // ---- stage input row j=0 (r = h0-1) into Ib[cur]
        {
            int r = h0 - 1;
            if (r >= 0) {
                const unsigned short* usrc = U + ubase + (((size_t)r) << 15) + cc * 32;
                for (int i = tid; i < 1032; i += 1024) {
                    int p = i >> 2, q = i & 3;
                    uint4 v = (p == 0 || p == 257) ? make_uint4(0u, 0u, 0u, 0u)
                                                   : *(const uint4*)&usrc[(((size_t)(p - 1)) << 7) + q * 8];
                    *(uint4*)&Ib[cur][p][q * 8] = v;
                }
            }
        }
        __syncthreads();

        for (int j = 0; j < 6; j++) {
            // ---- early-issue loads for next input row (hidden under compute)
            int rn = h0 + j;              // row staged for iteration j+1
            bool have = (j < 5) && (rn <= 255);
            uint4 s0;
            int i0 = tid;                 // covers p = 0..255
            if (have) {
                const unsigned short* usrc = U + ubase + (((size_t)rn) << 15) + cc * 32;
                int p = i0 >> 2, q = i0 & 3;
                s0 = (p == 0) ? make_uint4(0u, 0u, 0u, 0u)
                              : *(const uint4*)&usrc[(((size_t)(p - 1)) << 7) + q * 8];
            }
            // ---- compute stage j: input row r = h0-1+j, this wave's kh = j-rowsel
            int r = h0 - 1 + j;
            int kh = j - rowsel;
            if (kh >= 0 && kh <= 2 && r >= 0 && r <= 255) {
                __builtin_amdgcn_s_setprio(1);
#pragma unroll
                for (int kw = 0; kw < 3; kw++) {
                    s16x8 af[4], bfr[4];
#pragma unroll
                    for (int m = 0; m < 4; m++)
                        af[m] = *(const s16x8*)&Alds[kh][m * 16 + lr][kw * 32 + lq * 8];
#pragma unroll
                    for (int n = 0; n < 4; n++)
                        bfr[n] = *(const s16x8*)&Ib[cur][(pq << 6) + n * 16 + lr + kw][lq * 8];
#pragma unroll
                    for (int m = 0; m < 4; m++)
#pragma unroll
                        for (int n = 0; n < 4; n++)
                            acc[m][n] = __builtin_amdgcn_mfma_f32_16x16x32_bf16(af[m], bfr[n], acc[m][n], 0, 0, 0);
                }
                __builtin_amdgcn_s_setprio(0);
            }
            // ---- write staged regs into the other buffer + tail (p=256,257)
            if (have) {
                { int p = i0 >> 2, q = i0 & 3; *(uint4*)&Ib[cur ^ 1][p][q * 8] = s0; }
                if (tid < 8) {
                    int i2 = tid + 1024;
                    int p = i2 >> 2, q = i2 & 3;
                    const unsigned short* usrc = U + ubase + (((size_t)rn) << 15) + cc * 32;
                    uint4 v = (p == 257) ? make_uint4(0u, 0u, 0u, 0u)
                                         : *(const uint4*)&usrc[(((size_t)(p - 1)) << 7) + q * 8];
                    *(uint4*)&Ib[cur ^ 1][p][q * 8] = v;
                }
            }
            __syncthreads();
            if (j < 5) cur ^= 1;
        }
    }

    // epilogue: C/D layout col=lane&15 (pixel), row=(lane>>4)*4+jj (cout)
#pragma unroll
    for (int m = 0; m < 4; m++) {
#pragma unroll
        for (int jj = 0; jj < 4; jj++) {
            int co = m * 16 + lq * 4 + jj;
            float bias = b1[co] + 4.f * b2[co];
#pragma unroll
            for (int n = 0; n < 4; n++) {
                int wpix = (pq << 6) + n * 16 + lr;
                out[(((size_t)(b * 64 + co)) << 16) + (o << 8) + wpix] = acc[m][n][jj] + bias;
            }
        }
    }
}

// ---------------------------------------------------------------------------
// Fallback (only if ws too small): direct conv, recomputing quad on the fly.
// ---------------------------------------------------------------------------
__global__ void fallback_conv(const float* __restrict__ x,
                              const float* __restrict__ w1, const float* __restrict__ b1,
                              const float* __restrict__ w2, const float* __restrict__ b2,
                              float* __restrict__ out) {
    size_t idx = (size_t)blockIdx.x * 256 + threadIdx.x;
    int w = idx & 255;
    int h = (int)(idx >> 8) & 255;
    int co = (int)(idx >> 16) & 63;
    int b = (int)(idx >> 22);
    float acc = b1[co] + 4.f * b2[co];
    const float* xb = x + (((size_t)b * 64) << 16);
    for (int ci = 0; ci < 64; ci++) {
        const float* xp = xb + (((size_t)ci) << 16);
        for (int kh = 0; kh < 3; kh++) {
            int hh = h + kh - 1;
            if (hh < 0 || hh > 255) continue;
            for (int kw = 0; kw < 3; kw++) {
                int ww = w + kw - 1;
                if (ww < 0 || ww > 255) continue;
                float xv = xp[(hh << 8) + ww];
                float g1 = w1[((co * 64 + ci) * 3 + kh) * 3 + kw];
                float g2 = w2[((co * 64 + ci) * 3 + kh) * 3 + kw];
                int hm = (hh + 255) & 255, hp = (hh + 1) & 255, wm = (ww + 255) & 255;
                float q = clip1(xv * xp[(hm << 8) + ww]) + clip1(xv * xp[(hp << 8) + wm])
                        + clip1(xv * xp[(hh << 8) + wm]) + clip1(xv * xp[(hm << 8) + wm]);
                acc = fmaf(g1, xv, acc);
                acc = fmaf(g2, q, acc);
            }
        }
    }
    out[idx] = acc;
}

extern "C" void kernel_launch(void* const* d_in, const int* in_sizes, int n_in,
                              void* d_out, int out_size, void* d_ws, size_t ws_size,
                              hipStream_t stream) {
    const float* x  = (const float*)d_in[0];
    const float* w1 = (const float*)d_in[1];
    const float* b1 = (const float*)d_in[2];
    const float* w2 = (const float*)d_in[3];
    const float* b2 = (const float*)d_in[4];
    float* out = (float*)d_out;

    const size_t WB_BYTES = 262144;
    const size_t U_BYTES  = (size_t)8 * 256 * 256 * 128 * 2;  // 128 MiB
    if (ws_size >= WB_BYTES + U_BYTES) {
        unsigned short* Wb = (unsigned short*)d_ws;
        unsigned short* U  = (unsigned short*)((char*)d_ws + WB_BYTES);
        prep_w<<<dim3(288), dim3(256), 0, stream>>>(w1, w2, Wb);
        prep_u3<<<dim3(4096), dim3(512), 0, stream>>>(x, U);
        conv4<<<dim3(512), dim3(1024), 0, stream>>>(U, Wb, b1, b2, out);
    } else {
        fallback_conv<<<dim3(131072), dim3(256), 0, stream>>>(x, w1, b1, w2, b2, out);
    }
}

// Round 7
// 164.961 us; speedup vs baseline: 1.1695x; 1.1695x over previous
//
#include <hip/hip_runtime.h>
#include <stdint.h>

// Volterra layer: out = conv3x3(x,w1) + conv3x3(quad,w2) + (b1 + 4*b2)
// quad = sum over 4 shifts of clip(x * circular_shift(x), -1, 1)
// B=8, C=64, H=W=256. Convs are zero-pad SAME; shifts are circular.

typedef short s16x8 __attribute__((ext_vector_type(8)));
typedef float f32x4 __attribute__((ext_vector_type(4)));

__device__ __forceinline__ float clip1(float v) { return fminf(fmaxf(v, -1.f), 1.f); }

__device__ __forceinline__ unsigned short f2bf(float f) {
    union { float f; unsigned u; } v; v.f = f;
    unsigned u = v.u;
    return (unsigned short)((u + 0x7fffu + ((u >> 16) & 1u)) >> 16);
}

__device__ __forceinline__ float bf2f(unsigned short u) {
    union { unsigned v; float f; } t; t.v = ((unsigned)u) << 16; return t.f;
}

// ---------------------------------------------------------------------------
// Kernel 1: weights -> bf16, layout Wb[kh][cc][co][kw*32+cci]
// ---------------------------------------------------------------------------
__global__ void prep_w(const float* __restrict__ w1, const float* __restrict__ w2,
                       unsigned short* __restrict__ Wb) {
    int idx = blockIdx.x * 256 + threadIdx.x;   // exactly 73728 threads
    int kk = idx % 96;
    int rest = idx / 96;
    int co = rest & 63; rest >>= 6;
    int cc = rest & 3;
    int kh = rest >> 2;
    int kw = kk >> 5;
    int cci = kk & 31;
    int c2 = cc * 32 + cci;
    const float* src = (c2 < 64) ? w1 : w2;
    int ci = c2 & 63;
    Wb[idx] = f2bf(src[((co * 64 + ci) * 3 + kh) * 3 + kw]);
}

// ---------------------------------------------------------------------------
// Kernel 2: LDS-transposed quad/pack (R2 version -- best measured). Block =
// (b,h) [XCD-swizzled], 512 thr.
// U[(b*256+h)*256+w][c2]: c2 0-63 = bf16(x), 64-127 = bf16(quad).
// ---------------------------------------------------------------------------
__global__ __launch_bounds__(512, 1) void prep_u2(const float* __restrict__ x,
                                                  unsigned short* __restrict__ U) {
    __shared__ unsigned short X[3][64][268];
    int bid = blockIdx.x;
    int bh = ((bid & 7) << 8) + (bid >> 3);   // XCD k -> batch image k
    int b = bh >> 8, h = bh & 255;
    int tid = threadIdx.x;

    for (int it = 0; it < 24; ++it) {
        int idx = tid + (it << 9);
        int w4 = idx & 63;
        int c  = (idx >> 6) & 63;
        int r  = idx >> 12;
        int gr = (h + r + 255) & 255;
        const float4 v = *(const float4*)(x + (((size_t)(b * 64 + c)) << 16)
                                            + (gr << 8) + (w4 << 2));
        ushort4 p;
        p.x = f2bf(v.x); p.y = f2bf(v.y); p.z = f2bf(v.z); p.w = f2bf(v.w);
        *(ushort4*)&X[r][c][w4 << 2] = p;
    }
    __syncthreads();

    int c  = tid & 63;
    int wv = tid >> 6;
    int p0 = wv << 5;
    int pm0 = (p0 + 255) & 255;
    float pxc = bf2f(X[1][c][pm0]);
    float pxu = bf2f(X[0][c][pm0]);
    float pxd = bf2f(X[2][c][pm0]);
    size_t base = ((size_t)bh) << 8;
#pragma unroll 4
    for (int i = 0; i < 32; ++i) {
        int p = p0 + i;
        unsigned short xcb = X[1][c][p];
        float xc = bf2f(xcb);
        float xu = bf2f(X[0][c][p]);
        float xd = bf2f(X[2][c][p]);
        float q = clip1(xc * xu) + clip1(xc * pxd) + clip1(xc * pxc) + clip1(xc * pxu);
        size_t po = (base + p) << 7;
        U[po + c]      = xcb;
        U[po + 64 + c] = f2bf(q);
        pxc = xc; pxu = xu; pxd = xd;
    }
}

// ---------------------------------------------------------------------------
// Kernel 3 (v5): input-row-stationary implicit-GEMM conv, 4 rows x 128 px per
// block, 512 thr = 8 waves (rowsel 0..3 x pixel-half 0..1). Wave tile 64co x
// 64px (acc unchanged: 64 AGPR + ~64 arch = 128/wave = 4 waves/SIMD).
// LDS 60.7 KB -> TWO resident blocks/CU (was 1): barrier bubbles of one block
// overlap the sibling's compute. Proven linear layouts: Ilds stride 40,
// Alds stride 104 (2-dwords/bank floor per 16-lane phase).
// ---------------------------------------------------------------------------
__global__ __launch_bounds__(512, 4) void conv5(
        const unsigned short* __restrict__ U,
        const unsigned short* __restrict__ Wb,
        const float* __restrict__ b1, const float* __restrict__ b2,
        float* __restrict__ out) {
    __shared__ unsigned short Alds[3][64][104];   // 39936 B
    __shared__ unsigned short Ib[2][130][40];     // 20800 B  (total 60736 B)

    int bid = blockIdx.x;                          // 1024 blocks
    int logical = ((bid & 7) << 7) + (bid >> 3);   // XCD k -> batch image k
    int b = logical >> 7;
    int rem = logical & 127;
    int h0 = (rem >> 1) << 2;                      // 4 output rows h0..h0+3
    int whalf = rem & 1;
    int w0 = whalf << 7;                           // pixel-half base 0 / 128
    int tid = threadIdx.x;
    int wid = tid >> 6;
    int ln = tid & 63;
    int lr = ln & 15;        // MFMA A-row / C col
    int lq = ln >> 4;        // MFMA k-group / C row-group
    int rowsel = wid >> 1;   // which of the 4 output rows
    int pq = wid & 1;        // pixel 64-quarter within the 128-px half
    int o = h0 + rowsel;

    f32x4 acc[4][4];
#pragma unroll
    for (int m = 0; m < 4; m++)
#pragma unroll
        for (int n = 0; n < 4; n++) {
            acc[m][n][0] = 0.f; acc[m][n][1] = 0.f; acc[m][n][2] = 0.f; acc[m][n][3] = 0.f;
        }

    const size_t ubase = ((size_t)b) << 23;

    int cur = 0;
    for (int cc = 0; cc < 4; cc++) {
        // ---- stage weights for all 3 kh of this cc
        for (int i = tid; i < 2304; i += 512) {
            int kh = i / 768;
            int remw = i - kh * 768;
            int co = remw / 12;
            int kk = (remw - co * 12) << 3;
            *(uint4*)&Alds[kh][co][kk] =
                *(const uint4*)&Wb[(((size_t)((kh * 4 + cc) * 64 + co)) * 96) + kk];
        }
        // ---- stage input row j=0 (r = h0-1) into Ib[cur]: 130 px x 4 quads
        {
            int r = h0 - 1;
            if (r >= 0) {
                const unsigned short* usrc = U + ubase + (((size_t)r) << 15) + cc * 32;
                for (int i = tid; i < 520; i += 512) {
                    int p = i >> 2, q = i & 3;
                    int gcol = w0 + p - 1;
                    uint4 v = (gcol < 0 || gcol > 255) ? make_uint4(0u, 0u, 0u, 0u)
                              : *(const uint4*)&usrc[(((size_t)gcol) << 7) + q * 8];
                    *(uint4*)&Ib[cur][p][q * 8] = v;
                }
            }
        }
        __syncthreads();

        for (int j = 0; j < 6; j++) {
            // ---- early-issue loads for next input row (hidden under compute)
            int rn = h0 + j;              // row staged for iteration j+1
            bool have = (j < 5) && (rn <= 255);
            uint4 s0;
            if (have) {
                const unsigned short* usrc = U + ubase + (((size_t)rn) << 15) + cc * 32;
                int p = tid >> 2, q = tid & 3;
                int gcol = w0 + p - 1;
                s0 = (gcol < 0 || gcol > 255) ? make_uint4(0u, 0u, 0u, 0u)
                     : *(const uint4*)&usrc[(((size_t)gcol) << 7) + q * 8];
            }
            // ---- compute stage j: input row r = h0-1+j, this wave's kh = j-rowsel
            int r = h0 - 1 + j;
            int kh = j - rowsel;
            if (kh >= 0 && kh <= 2 && r >= 0 && r <= 255) {
                __builtin_amdgcn_s_setprio(1);
#pragma unroll
                for (int kw = 0; kw < 3; kw++) {
                    s16x8 af[4], bfr[4];
#pragma unroll
                    for (int m = 0; m < 4; m++)
                        af[m] = *(const s16x8*)&Alds[kh][m * 16 + lr][kw * 32 + lq * 8];
#pragma unroll
                    for (int n = 0; n < 4; n++)
                        bfr[n] = *(const s16x8*)&Ib[cur][(pq << 6) + n * 16 + lr + kw][lq * 8];
#pragma unroll
                    for (int m = 0; m < 4; m++)
#pragma unroll
                        for (int n = 0; n < 4; n++)
                            acc[m][n] = __builtin_amdgcn_mfma_f32_16x16x32_bf16(af[m], bfr[n], acc[m][n], 0, 0, 0);
                }
                __builtin_amdgcn_s_setprio(0);
            }
            // ---- write staged regs into the other buffer + tail (p=128,129)
            if (have) {
                { int p = tid >> 2, q = tid & 3; *(uint4*)&Ib[cur ^ 1][p][q * 8] = s0; }
                if (tid < 8) {
                    int i2 = tid + 512;
                    int p = i2 >> 2, q = i2 & 3;
                    int gcol = w0 + p - 1;
                    const unsigned short* usrc = U + ubase + (((size_t)rn) << 15) + cc * 32;
                    uint4 v = (gcol < 0 || gcol > 255) ? make_uint4(0u, 0u, 0u, 0u)
                              : *(const uint4*)&usrc[(((size_t)gcol) << 7) + q * 8];
                    *(uint4*)&Ib[cur ^ 1][p][q * 8] = v;
                }
            }
            __syncthreads();
            if (j < 5) cur ^= 1;
        }
    }

    // epilogue: C/D layout col=lane&15 (pixel), row=(lane>>4)*4+jj (cout)
#pragma unroll
    for (int m = 0; m < 4; m++) {
#pragma unroll
        for (int jj = 0; jj < 4; jj++) {
            int co = m * 16 + lq * 4 + jj;
            float bias = b1[co] + 4.f * b2[co];
#pragma unroll
            for (int n = 0; n < 4; n++) {
                int wpix = w0 + (pq << 6) + n * 16 + lr;
                out[(((size_t)(b * 64 + co)) << 16) + (o << 8) + wpix] = acc[m][n][jj] + bias;
            }
        }
    }
}

// ---------------------------------------------------------------------------
// Fallback (only if ws too small): direct conv, recomputing quad on the fly.
// ---------------------------------------------------------------------------
__global__ void fallback_conv(const float* __restrict__ x,
                              const float* __restrict__ w1, const float* __restrict__ b1,
                              const float* __restrict__ w2, const float* __restrict__ b2,
                              float* __restrict__ out) {
    size_t idx = (size_t)blockIdx.x * 256 + threadIdx.x;
    int w = idx & 255;
    int h = (int)(idx >> 8) & 255;
    int co = (int)(idx >> 16) & 63;
    int b = (int)(idx >> 22);
    float acc = b1[co] + 4.f * b2[co];
    const float* xb = x + (((size_t)b * 64) << 16);
    for (int ci = 0; ci < 64; ci++) {
        const float* xp = xb + (((size_t)ci) << 16);
        for (int kh = 0; kh < 3; kh++) {
            int hh = h + kh - 1;
            if (hh < 0 || hh > 255) continue;
            for (int kw = 0; kw < 3; kw++) {
                int ww = w + kw - 1;
                if (ww < 0 || ww > 255) continue;
                float xv = xp[(hh << 8) + ww];
                float g1 = w1[((co * 64 + ci) * 3 + kh) * 3 + kw];
                float g2 = w2[((co * 64 + ci) * 3 + kh) * 3 + kw];
                int hm = (hh + 255) & 255, hp = (hh + 1) & 255, wm = (ww + 255) & 255;
                float q = clip1(xv * xp[(hm << 8) + ww]) + clip1(xv * xp[(hp << 8) + wm])
                        + clip1(xv * xp[(hh << 8) + wm]) + clip1(xv * xp[(hm << 8) + wm]);
                acc = fmaf(g1, xv, acc);
                acc = fmaf(g2, q, acc);
            }
        }
    }
    out[idx] = acc;
}

extern "C" void kernel_launch(void* const* d_in, const int* in_sizes, int n_in,
                              void* d_out, int out_size, void* d_ws, size_t ws_size,
                              hipStream_t stream) {
    const float* x  = (const float*)d_in[0];
    const float* w1 = (const float*)d_in[1];
    const float* b1 = (const float*)d_in[2];
    const float* w2 = (const float*)d_in[3];
    const float* b2 = (const float*)d_in[4];
    float* out = (float*)d_out;

    const size_t WB_BYTES = 262144;
    const size_t U_BYTES  = (size_t)8 * 256 * 256 * 128 * 2;  // 128 MiB
    if (ws_size >= WB_BYTES + U_BYTES) {
        unsigned short* Wb = (unsigned short*)d_ws;
        unsigned short* U  = (unsigned short*)((char*)d_ws + WB_BYTES);
        prep_w<<<dim3(288), dim3(256), 0, stream>>>(w1, w2, Wb);
        prep_u2<<<dim3(2048), dim3(512), 0, stream>>>(x, U);
        conv5<<<dim3(1024), dim3(512), 0, stream>>>(U, Wb, b1, b2, out);
    } else {
        fallback_conv<<<dim3(131072), dim3(256), 0, stream>>>(x, w1, b1, w2, b2, out);
    }
}